// Round 1
// baseline (910.102 us; speedup 1.0000x reference)
//
#include <hip/hip_runtime.h>

#define NLOCAL 55000
#define NOWNED 50000
#define NEDGES 800000
#define INC 128
#define HIDC 128
#define OUTC 64

static __device__ __forceinline__ void atomic_fadd(float* p, float v) {
    __hip_atomic_fetch_add(p, v, __ATOMIC_RELAXED, __HIP_MEMORY_SCOPE_AGENT);
}

// ---------------- layer 1 scatter: agg1[row] += d[col] * x[col]  (128 ch) ----------------
// one wave (64 lanes) per edge, 2 floats per lane
__global__ __launch_bounds__(256) void scatter1_k(const float* __restrict__ x,
                                                  const float* __restrict__ deg,
                                                  const int* __restrict__ er,
                                                  const int* __restrict__ ec,
                                                  float* __restrict__ agg1) {
    const int e = (blockIdx.x * 256 + threadIdx.x) >> 6;
    const int lane = threadIdx.x & 63;
    if (e >= NEDGES) return;
    const int row = er[e];
    if (row >= NOWNED) return;         // only owned destination rows matter
    const int col = ec[e];
    const float dc = deg[col];
    const float2 v = *(const float2*)(x + (size_t)col * INC + lane * 2);
    float* dst = agg1 + (size_t)row * INC + lane * 2;
    atomic_fadd(dst + 0, v.x * dc);
    atomic_fadd(dst + 1, v.y * dc);
}

// ---------------- gemm1: z = relu(d * (agg1 @ w1) + b1) * d   [NOWNED x 128] ----------------
// 64 rows x 128 cols per block, 256 threads, each thread 4 rows x 8 cols
__global__ __launch_bounds__(256) void gemm1_k(const float* __restrict__ agg1,
                                               const float* __restrict__ w1,
                                               const float* __restrict__ b1,
                                               const float* __restrict__ deg,
                                               float* __restrict__ z) {
    __shared__ float lds[64][132];     // +4 pad, keeps float4 alignment
    const int t = threadIdx.x;
    const int r0 = blockIdx.x * 64;
    #pragma unroll
    for (int i = 0; i < 8; ++i) {
        const int idx = t + i * 256;           // 0..2047 -> 64 rows x 32 float4
        const int r = idx >> 5;
        const int k0 = (idx & 31) << 2;
        const int gr = r0 + r;
        float4 v = make_float4(0.f, 0.f, 0.f, 0.f);
        if (gr < NOWNED) v = *(const float4*)(agg1 + (size_t)gr * INC + k0);
        *(float4*)(&lds[r][k0]) = v;
    }
    __syncthreads();
    const int cg = t & 15;   // cols cg*8 .. cg*8+7
    const int rg = t >> 4;   // rows rg*4 .. rg*4+3
    float acc[4][8];
    #pragma unroll
    for (int i = 0; i < 4; ++i)
        #pragma unroll
        for (int j = 0; j < 8; ++j) acc[i][j] = 0.f;

    #pragma unroll 8
    for (int k = 0; k < 128; ++k) {
        float av[4];
        #pragma unroll
        for (int i = 0; i < 4; ++i) av[i] = lds[rg * 4 + i][k];   // broadcast reads
        const float* wp = w1 + k * HIDC + cg * 8;
        const float4 w0 = *(const float4*)wp;
        const float4 w1v = *(const float4*)(wp + 4);
        const float wv[8] = {w0.x, w0.y, w0.z, w0.w, w1v.x, w1v.y, w1v.z, w1v.w};
        #pragma unroll
        for (int i = 0; i < 4; ++i)
            #pragma unroll
            for (int j = 0; j < 8; ++j)
                acc[i][j] = fmaf(av[i], wv[j], acc[i][j]);
    }
    #pragma unroll
    for (int i = 0; i < 4; ++i) {
        const int gr = r0 + rg * 4 + i;
        if (gr >= NOWNED) continue;
        const float di = deg[gr];
        float o[8];
        #pragma unroll
        for (int j = 0; j < 8; ++j) {
            const int gc = cg * 8 + j;
            float v = fmaf(di, acc[i][j], b1[gc]);   // d * dot + b1
            o[j] = fmaxf(v, 0.f) * di;               // relu, then fold next layer's d-scale
        }
        float4* zp = (float4*)(z + (size_t)gr * HIDC + cg * 8);
        zp[0] = make_float4(o[0], o[1], o[2], o[3]);
        zp[1] = make_float4(o[4], o[5], o[6], o[7]);
    }
}

// ---------------- gemm2: h2 = z @ w2   [NOWNED x 64] ----------------
// 128 rows x 64 cols per block, 256 threads, each thread 8 rows x 4 cols
__global__ __launch_bounds__(256) void gemm2_k(const float* __restrict__ zz,
                                               const float* __restrict__ w2,
                                               float* __restrict__ h2) {
    __shared__ float lds[128][132];
    const int t = threadIdx.x;
    const int r0 = blockIdx.x * 128;
    #pragma unroll
    for (int i = 0; i < 16; ++i) {
        const int idx = t + i * 256;           // 0..4095 -> 128 rows x 32 float4
        const int r = idx >> 5;
        const int k0 = (idx & 31) << 2;
        const int gr = r0 + r;
        float4 v = make_float4(0.f, 0.f, 0.f, 0.f);
        if (gr < NOWNED) v = *(const float4*)(zz + (size_t)gr * HIDC + k0);
        *(float4*)(&lds[r][k0]) = v;
    }
    __syncthreads();
    const int cg = t & 15;   // cols cg*4 .. cg*4+3
    const int rg = t >> 4;   // rows rg*8 .. rg*8+7
    float acc[8][4];
    #pragma unroll
    for (int i = 0; i < 8; ++i)
        #pragma unroll
        for (int j = 0; j < 4; ++j) acc[i][j] = 0.f;

    #pragma unroll 8
    for (int k = 0; k < 128; ++k) {
        float av[8];
        #pragma unroll
        for (int i = 0; i < 8; ++i) av[i] = lds[rg * 8 + i][k];
        const float4 wv = *(const float4*)(w2 + k * OUTC + cg * 4);
        const float wj[4] = {wv.x, wv.y, wv.z, wv.w};
        #pragma unroll
        for (int i = 0; i < 8; ++i)
            #pragma unroll
            for (int j = 0; j < 4; ++j)
                acc[i][j] = fmaf(av[i], wj[j], acc[i][j]);
    }
    #pragma unroll
    for (int i = 0; i < 8; ++i) {
        const int gr = r0 + rg * 8 + i;
        if (gr >= NOWNED) continue;
        *(float4*)(h2 + (size_t)gr * OUTC + cg * 4) =
            make_float4(acc[i][0], acc[i][1], acc[i][2], acc[i][3]);
    }
}

// ---------------- layer 2 scatter: agg2[row] += h2[col]  (64 ch) ----------------
__global__ __launch_bounds__(256) void scatter2_k(const float* __restrict__ h2,
                                                  const int* __restrict__ er,
                                                  const int* __restrict__ ec,
                                                  float* __restrict__ agg2) {
    const int e = (blockIdx.x * 256 + threadIdx.x) >> 6;
    const int lane = threadIdx.x & 63;
    if (e >= NEDGES) return;
    const int row = er[e];
    const int col = ec[e];
    if (row >= NOWNED || col >= NOWNED) return;   // col>=NOWNED rows of x2 are zero
    const float v = h2[(size_t)col * OUTC + lane];
    atomic_fadd(agg2 + (size_t)row * OUTC + lane, v);
}

// ---------------- epilogue: out = agg2 * d + b2 ----------------
__global__ __launch_bounds__(256) void epilogue_k(const float* __restrict__ agg2,
                                                  const float* __restrict__ deg,
                                                  const float* __restrict__ b2,
                                                  float* __restrict__ out) {
    const int gid = blockIdx.x * 256 + threadIdx.x;   // one float4 each
    if (gid >= NOWNED * OUTC / 4) return;
    const int i = gid >> 4;
    const int j0 = (gid & 15) << 2;
    const float di = deg[i];
    const float4 a = *(const float4*)(agg2 + (size_t)i * OUTC + j0);
    const float4 b = *(const float4*)(b2 + j0);
    const float4 o = make_float4(fmaf(a.x, di, b.x), fmaf(a.y, di, b.y),
                                 fmaf(a.z, di, b.z), fmaf(a.w, di, b.w));
    *(float4*)(out + (size_t)i * OUTC + j0) = o;
}

extern "C" void kernel_launch(void* const* d_in, const int* in_sizes, int n_in,
                              void* d_out, int out_size, void* d_ws, size_t ws_size,
                              hipStream_t stream) {
    const float* x   = (const float*)d_in[0];
    const float* deg = (const float*)d_in[1];
    const float* w1  = (const float*)d_in[2];
    const float* b1  = (const float*)d_in[3];
    const float* w2  = (const float*)d_in[4];
    const float* b2  = (const float*)d_in[5];
    const int* er    = (const int*)d_in[6];
    const int* ec    = (const int*)d_in[7];
    float* out = (float*)d_out;

    char* ws = (char*)d_ws;
    float* agg1 = (float*)(ws);                       // 25.6 MB  [NOWNED x 128]
    float* z    = (float*)(ws + 25600000);            // 25.6 MB  [NOWNED x 128]
    float* h2   = (float*)(ws);                       // 12.8 MB  (aliases dead agg1)
    float* agg2 = (float*)(ws + 12800000);            // 12.8 MB  (aliases dead agg1)

    hipMemsetAsync(agg1, 0, (size_t)NOWNED * INC * sizeof(float), stream);
    scatter1_k<<<NEDGES / 4, 256, 0, stream>>>(x, deg, er, ec, agg1);
    gemm1_k<<<(NOWNED + 63) / 64, 256, 0, stream>>>(agg1, w1, b1, deg, z);
    // agg1 is dead from here; h2/agg2 alias it (stream-ordered)
    hipMemsetAsync(agg2, 0, (size_t)NOWNED * OUTC * sizeof(float), stream);
    gemm2_k<<<(NOWNED + 127) / 128, 256, 0, stream>>>(z, w2, h2);
    scatter2_k<<<NEDGES / 4, 256, 0, stream>>>(h2, er, ec, agg2);
    epilogue_k<<<(NOWNED * OUTC / 4 + 255) / 256, 256, 0, stream>>>(agg2, deg, b2, out);
}

// Round 2
// 465.686 us; speedup vs baseline: 1.9543x; 1.9543x over previous
//
#include <hip/hip_runtime.h>

#define NLOCAL 55000
#define NOWNED 50000
#define NEDGES 800000
#define INC 128
#define HIDC 128
#define OUTC 64

// ================= CSR build =================

__global__ __launch_bounds__(256) void hist_k(const int* __restrict__ er,
                                              int* __restrict__ counts) {
    const int e = blockIdx.x * 256 + threadIdx.x;
    if (e >= NEDGES) return;
    const int row = er[e];
    if (row < NOWNED) atomicAdd(&counts[row], 1);
}

// one 1024-thread block; two-pass exclusive scan of counts[0..NOWNED) -> offsets[0..NOWNED]
__global__ __launch_bounds__(1024) void scan_k(const int* __restrict__ counts,
                                               int* __restrict__ offsets) {
    __shared__ int partial[1024];
    const int t = threadIdx.x;
    const int CH = (NOWNED + 1023) / 1024;  // 49
    const int base = t * CH;
    int s = 0;
    for (int i = 0; i < CH; ++i) {
        const int idx = base + i;
        if (idx < NOWNED) s += counts[idx];
    }
    partial[t] = s;
    __syncthreads();
    // Hillis-Steele inclusive scan
    for (int off = 1; off < 1024; off <<= 1) {
        int v = (t >= off) ? partial[t - off] : 0;
        __syncthreads();
        partial[t] += v;
        __syncthreads();
    }
    int run = (t == 0) ? 0 : partial[t - 1];
    for (int i = 0; i < CH; ++i) {
        const int idx = base + i;
        if (idx < NOWNED) {
            offsets[idx] = run;
            run += counts[idx];
        }
    }
    if (t == 1023) offsets[NOWNED] = partial[1023];
}

__global__ __launch_bounds__(256) void fill_k(const int* __restrict__ er,
                                              const int* __restrict__ ec,
                                              const int* __restrict__ offsets,
                                              int* __restrict__ cursor,
                                              int* __restrict__ cols_sorted) {
    const int e = blockIdx.x * 256 + threadIdx.x;
    if (e >= NEDGES) return;
    const int row = er[e];
    if (row >= NOWNED) return;
    const int p = atomicAdd(&cursor[row], 1);
    cols_sorted[offsets[row] + p] = ec[e];
}

// ================= layer-1 gather: agg1[r] = sum_e deg[col]*x[col]  (128 ch) =================
// one wave per destination row, 2 floats/lane; single coalesced row write
__global__ __launch_bounds__(256) void gather1_k(const float* __restrict__ x,
                                                 const float* __restrict__ deg,
                                                 const int* __restrict__ offsets,
                                                 const int* __restrict__ cols,
                                                 float* __restrict__ agg1) {
    const int w = (blockIdx.x * 256 + threadIdx.x) >> 6;
    const int lane = threadIdx.x & 63;
    if (w >= NOWNED) return;
    const int beg = offsets[w];
    const int end = offsets[w + 1];
    float ax = 0.f, ay = 0.f;
    for (int e = beg; e < end; ++e) {
        const int col = cols[e];
        const float dc = deg[col];
        const float2 v = *(const float2*)(x + (size_t)col * INC + lane * 2);
        ax = fmaf(v.x, dc, ax);
        ay = fmaf(v.y, dc, ay);
    }
    *(float2*)(agg1 + (size_t)w * INC + lane * 2) = make_float2(ax, ay);
}

// ================= gemm1: z = relu(d*(agg1@w1)+b1)*d  [NOWNED x 128] =================
__global__ __launch_bounds__(256) void gemm1_k(const float* __restrict__ agg1,
                                               const float* __restrict__ w1,
                                               const float* __restrict__ b1,
                                               const float* __restrict__ deg,
                                               float* __restrict__ z) {
    __shared__ float lds[64][132];
    const int t = threadIdx.x;
    const int r0 = blockIdx.x * 64;
    #pragma unroll
    for (int i = 0; i < 8; ++i) {
        const int idx = t + i * 256;
        const int r = idx >> 5;
        const int k0 = (idx & 31) << 2;
        const int gr = r0 + r;
        float4 v = make_float4(0.f, 0.f, 0.f, 0.f);
        if (gr < NOWNED) v = *(const float4*)(agg1 + (size_t)gr * INC + k0);
        *(float4*)(&lds[r][k0]) = v;
    }
    __syncthreads();
    const int cg = t & 15;
    const int rg = t >> 4;
    float acc[4][8];
    #pragma unroll
    for (int i = 0; i < 4; ++i)
        #pragma unroll
        for (int j = 0; j < 8; ++j) acc[i][j] = 0.f;

    #pragma unroll 8
    for (int k = 0; k < 128; ++k) {
        float av[4];
        #pragma unroll
        for (int i = 0; i < 4; ++i) av[i] = lds[rg * 4 + i][k];
        const float* wp = w1 + k * HIDC + cg * 8;
        const float4 w0 = *(const float4*)wp;
        const float4 w1v = *(const float4*)(wp + 4);
        const float wv[8] = {w0.x, w0.y, w0.z, w0.w, w1v.x, w1v.y, w1v.z, w1v.w};
        #pragma unroll
        for (int i = 0; i < 4; ++i)
            #pragma unroll
            for (int j = 0; j < 8; ++j)
                acc[i][j] = fmaf(av[i], wv[j], acc[i][j]);
    }
    #pragma unroll
    for (int i = 0; i < 4; ++i) {
        const int gr = r0 + rg * 4 + i;
        if (gr >= NOWNED) continue;
        const float di = deg[gr];
        float o[8];
        #pragma unroll
        for (int j = 0; j < 8; ++j) {
            const int gc = cg * 8 + j;
            float v = fmaf(di, acc[i][j], b1[gc]);
            o[j] = fmaxf(v, 0.f) * di;   // relu + fold next layer's left d-scale
        }
        float4* zp = (float4*)(z + (size_t)gr * HIDC + cg * 8);
        zp[0] = make_float4(o[0], o[1], o[2], o[3]);
        zp[1] = make_float4(o[4], o[5], o[6], o[7]);
    }
}

// ================= gemm2: h2 = z @ w2  [NOWNED x 64] =================
__global__ __launch_bounds__(256) void gemm2_k(const float* __restrict__ zz,
                                               const float* __restrict__ w2,
                                               float* __restrict__ h2) {
    __shared__ float lds[128][132];
    const int t = threadIdx.x;
    const int r0 = blockIdx.x * 128;
    #pragma unroll
    for (int i = 0; i < 16; ++i) {
        const int idx = t + i * 256;
        const int r = idx >> 5;
        const int k0 = (idx & 31) << 2;
        const int gr = r0 + r;
        float4 v = make_float4(0.f, 0.f, 0.f, 0.f);
        if (gr < NOWNED) v = *(const float4*)(zz + (size_t)gr * HIDC + k0);
        *(float4*)(&lds[r][k0]) = v;
    }
    __syncthreads();
    const int cg = t & 15;
    const int rg = t >> 4;
    float acc[8][4];
    #pragma unroll
    for (int i = 0; i < 8; ++i)
        #pragma unroll
        for (int j = 0; j < 4; ++j) acc[i][j] = 0.f;

    #pragma unroll 8
    for (int k = 0; k < 128; ++k) {
        float av[8];
        #pragma unroll
        for (int i = 0; i < 8; ++i) av[i] = lds[rg * 8 + i][k];
        const float4 wv = *(const float4*)(w2 + k * OUTC + cg * 4);
        const float wj[4] = {wv.x, wv.y, wv.z, wv.w};
        #pragma unroll
        for (int i = 0; i < 8; ++i)
            #pragma unroll
            for (int j = 0; j < 4; ++j)
                acc[i][j] = fmaf(av[i], wj[j], acc[i][j]);
    }
    #pragma unroll
    for (int i = 0; i < 8; ++i) {
        const int gr = r0 + rg * 8 + i;
        if (gr >= NOWNED) continue;
        *(float4*)(h2 + (size_t)gr * OUTC + cg * 4) =
            make_float4(acc[i][0], acc[i][1], acc[i][2], acc[i][3]);
    }
}

// ================= layer-2 gather + epilogue: out[r] = deg[r]*sum(h2[col]) + b2 =================
__global__ __launch_bounds__(256) void gather2_k(const float* __restrict__ h2,
                                                 const float* __restrict__ deg,
                                                 const float* __restrict__ b2,
                                                 const int* __restrict__ offsets,
                                                 const int* __restrict__ cols,
                                                 float* __restrict__ out) {
    const int w = (blockIdx.x * 256 + threadIdx.x) >> 6;
    const int lane = threadIdx.x & 63;
    if (w >= NOWNED) return;
    const int beg = offsets[w];
    const int end = offsets[w + 1];
    float acc = 0.f;
    for (int e = beg; e < end; ++e) {
        const int col = cols[e];
        if (col < NOWNED)                      // x2 halo rows are zero
            acc += h2[(size_t)col * OUTC + lane];
    }
    out[(size_t)w * OUTC + lane] = fmaf(deg[w], acc, b2[lane]);
}

extern "C" void kernel_launch(void* const* d_in, const int* in_sizes, int n_in,
                              void* d_out, int out_size, void* d_ws, size_t ws_size,
                              hipStream_t stream) {
    const float* x   = (const float*)d_in[0];
    const float* deg = (const float*)d_in[1];
    const float* w1  = (const float*)d_in[2];
    const float* b1  = (const float*)d_in[3];
    const float* w2  = (const float*)d_in[4];
    const float* b2  = (const float*)d_in[5];
    const int* er    = (const int*)d_in[6];
    const int* ec    = (const int*)d_in[7];
    float* out = (float*)d_out;

    char* ws = (char*)d_ws;
    int*   cols_sorted = (int*)(ws);                    // 3.2 MB
    int*   offsets     = (int*)(ws + 3200000);          // 200 KB
    int*   counts      = (int*)(ws + 3400016);          // 200 KB (also cursor)
    float* agg1        = (float*)(ws + 4194304);        // 25.6 MB  [NOWNED x 128]
    float* z           = (float*)(ws + 29794304);       // 25.6 MB  [NOWNED x 128]
    float* h2          = (float*)(ws + 4194304);        // 12.8 MB (aliases dead agg1)

    // ---- CSR build ----
    hipMemsetAsync(counts, 0, NOWNED * sizeof(int), stream);
    hist_k<<<(NEDGES + 255) / 256, 256, 0, stream>>>(er, counts);
    scan_k<<<1, 1024, 0, stream>>>(counts, offsets);
    hipMemsetAsync(counts, 0, NOWNED * sizeof(int), stream);  // reuse as cursor
    fill_k<<<(NEDGES + 255) / 256, 256, 0, stream>>>(er, ec, offsets, counts, cols_sorted);

    // ---- layer 1 ----
    gather1_k<<<(NOWNED * 64 + 255) / 256, 256, 0, stream>>>(x, deg, offsets, cols_sorted, agg1);
    gemm1_k<<<(NOWNED + 63) / 64, 256, 0, stream>>>(agg1, w1, b1, deg, z);

    // ---- layer 2 ----  (agg1 dead; h2 aliases it)
    gemm2_k<<<(NOWNED + 127) / 128, 256, 0, stream>>>(z, w2, h2);
    gather2_k<<<(NOWNED * 64 + 255) / 256, 256, 0, stream>>>(h2, deg, b2, offsets, cols_sorted, out);
}

// Round 3
// 292.827 us; speedup vs baseline: 3.1080x; 1.5903x over previous
//
#include <hip/hip_runtime.h>

#define NLOCAL 55000
#define NOWNED 50000
#define NEDGES 800000
#define INC 128
#define HIDC 128
#define OUTC 64
#define CAP 64           // padded-CSR bucket capacity (max degree; P(exceed) ~ 1e-15)

// ================= padded-CSR build: cnt[row]++, cols_pad[row*CAP + p] = col =================
__global__ __launch_bounds__(256) void fill_k(const int* __restrict__ er,
                                              const int* __restrict__ ec,
                                              int* __restrict__ cnt,
                                              int* __restrict__ cols_pad) {
    const int e = blockIdx.x * 256 + threadIdx.x;
    if (e >= NEDGES) return;
    const int row = er[e];
    if (row >= NOWNED) return;                  // only owned destination rows matter
    const int p = atomicAdd(&cnt[row], 1);
    if (p < CAP) cols_pad[row * CAP + p] = ec[e];   // clamp guards OOB (never expected)
}

// ================= layer-1 gather: agg1[r] = sum_e deg[col]*x[col]  (128 ch) =================
// one wave per row, 2 floats/lane; cols+deg preloaded one-per-lane then shfl-broadcast
__global__ __launch_bounds__(256) void gather1_k(const float* __restrict__ x,
                                                 const float* __restrict__ deg,
                                                 const int* __restrict__ cnt,
                                                 const int* __restrict__ cols_pad,
                                                 float* __restrict__ agg1) {
    const int w = (blockIdx.x * 256 + threadIdx.x) >> 6;
    const int lane = threadIdx.x & 63;
    if (w >= NOWNED) return;
    int n = cnt[w];
    n = (n > CAP) ? CAP : n;
    const int mycol = (lane < n) ? cols_pad[w * CAP + lane] : 0;
    const float mydeg = (lane < n) ? deg[mycol] : 0.f;
    float ax = 0.f, ay = 0.f;
    for (int e = 0; e < n; ++e) {
        const int col = __shfl(mycol, e);
        const float dc = __shfl(mydeg, e);
        const float2 v = *(const float2*)(x + (size_t)col * INC + lane * 2);
        ax = fmaf(v.x, dc, ax);
        ay = fmaf(v.y, dc, ay);
    }
    *(float2*)(agg1 + (size_t)w * INC + lane * 2) = make_float2(ax, ay);
}

// ================= gemm1: z = relu(d*(agg1@w1)+b1)*d  [NOWNED x 128] =================
__global__ __launch_bounds__(256) void gemm1_k(const float* __restrict__ agg1,
                                               const float* __restrict__ w1,
                                               const float* __restrict__ b1,
                                               const float* __restrict__ deg,
                                               float* __restrict__ z) {
    __shared__ float lds[64][132];
    const int t = threadIdx.x;
    const int r0 = blockIdx.x * 64;
    #pragma unroll
    for (int i = 0; i < 8; ++i) {
        const int idx = t + i * 256;
        const int r = idx >> 5;
        const int k0 = (idx & 31) << 2;
        const int gr = r0 + r;
        float4 v = make_float4(0.f, 0.f, 0.f, 0.f);
        if (gr < NOWNED) v = *(const float4*)(agg1 + (size_t)gr * INC + k0);
        *(float4*)(&lds[r][k0]) = v;
    }
    __syncthreads();
    const int cg = t & 15;
    const int rg = t >> 4;
    float acc[4][8];
    #pragma unroll
    for (int i = 0; i < 4; ++i)
        #pragma unroll
        for (int j = 0; j < 8; ++j) acc[i][j] = 0.f;

    #pragma unroll 8
    for (int k = 0; k < 128; ++k) {
        float av[4];
        #pragma unroll
        for (int i = 0; i < 4; ++i) av[i] = lds[rg * 4 + i][k];
        const float* wp = w1 + k * HIDC + cg * 8;
        const float4 w0 = *(const float4*)wp;
        const float4 w1v = *(const float4*)(wp + 4);
        const float wv[8] = {w0.x, w0.y, w0.z, w0.w, w1v.x, w1v.y, w1v.z, w1v.w};
        #pragma unroll
        for (int i = 0; i < 4; ++i)
            #pragma unroll
            for (int j = 0; j < 8; ++j)
                acc[i][j] = fmaf(av[i], wv[j], acc[i][j]);
    }
    #pragma unroll
    for (int i = 0; i < 4; ++i) {
        const int gr = r0 + rg * 4 + i;
        if (gr >= NOWNED) continue;
        const float di = deg[gr];
        float o[8];
        #pragma unroll
        for (int j = 0; j < 8; ++j) {
            const int gc = cg * 8 + j;
            float v = fmaf(di, acc[i][j], b1[gc]);
            o[j] = fmaxf(v, 0.f) * di;   // relu + fold next layer's left d-scale
        }
        float4* zp = (float4*)(z + (size_t)gr * HIDC + cg * 8);
        zp[0] = make_float4(o[0], o[1], o[2], o[3]);
        zp[1] = make_float4(o[4], o[5], o[6], o[7]);
    }
}

// ================= gemm2: h2 = z @ w2  [NOWNED x 64] =================
__global__ __launch_bounds__(256) void gemm2_k(const float* __restrict__ zz,
                                               const float* __restrict__ w2,
                                               float* __restrict__ h2) {
    __shared__ float lds[128][132];
    const int t = threadIdx.x;
    const int r0 = blockIdx.x * 128;
    #pragma unroll
    for (int i = 0; i < 16; ++i) {
        const int idx = t + i * 256;
        const int r = idx >> 5;
        const int k0 = (idx & 31) << 2;
        const int gr = r0 + r;
        float4 v = make_float4(0.f, 0.f, 0.f, 0.f);
        if (gr < NOWNED) v = *(const float4*)(zz + (size_t)gr * HIDC + k0);
        *(float4*)(&lds[r][k0]) = v;
    }
    __syncthreads();
    const int cg = t & 15;
    const int rg = t >> 4;
    float acc[8][4];
    #pragma unroll
    for (int i = 0; i < 8; ++i)
        #pragma unroll
        for (int j = 0; j < 4; ++j) acc[i][j] = 0.f;

    #pragma unroll 8
    for (int k = 0; k < 128; ++k) {
        float av[8];
        #pragma unroll
        for (int i = 0; i < 8; ++i) av[i] = lds[rg * 8 + i][k];
        const float4 wv = *(const float4*)(w2 + k * OUTC + cg * 4);
        const float wj[4] = {wv.x, wv.y, wv.z, wv.w};
        #pragma unroll
        for (int i = 0; i < 8; ++i)
            #pragma unroll
            for (int j = 0; j < 4; ++j)
                acc[i][j] = fmaf(av[i], wj[j], acc[i][j]);
    }
    #pragma unroll
    for (int i = 0; i < 8; ++i) {
        const int gr = r0 + rg * 8 + i;
        if (gr >= NOWNED) continue;
        *(float4*)(h2 + (size_t)gr * OUTC + cg * 4) =
            make_float4(acc[i][0], acc[i][1], acc[i][2], acc[i][3]);
    }
}

// ================= layer-2 gather + epilogue: out[r] = deg[r]*sum(h2[col]) + b2 =================
__global__ __launch_bounds__(256) void gather2_k(const float* __restrict__ h2,
                                                 const float* __restrict__ deg,
                                                 const float* __restrict__ b2,
                                                 const int* __restrict__ cnt,
                                                 const int* __restrict__ cols_pad,
                                                 float* __restrict__ out) {
    const int w = (blockIdx.x * 256 + threadIdx.x) >> 6;
    const int lane = threadIdx.x & 63;
    if (w >= NOWNED) return;
    int n = cnt[w];
    n = (n > CAP) ? CAP : n;
    int c = (lane < n) ? cols_pad[w * CAP + lane] : 0;
    const float mywgt = (lane < n && c < NOWNED) ? 1.f : 0.f;  // x2 halo rows are zero
    if (c >= NOWNED) c = 0;                                    // clamp for safe load
    float acc = 0.f;
    for (int e = 0; e < n; ++e) {
        const int col = __shfl(c, e);
        const float wgt = __shfl(mywgt, e);
        acc = fmaf(wgt, h2[(size_t)col * OUTC + lane], acc);
    }
    out[(size_t)w * OUTC + lane] = fmaf(deg[w], acc, b2[lane]);
}

extern "C" void kernel_launch(void* const* d_in, const int* in_sizes, int n_in,
                              void* d_out, int out_size, void* d_ws, size_t ws_size,
                              hipStream_t stream) {
    const float* x   = (const float*)d_in[0];
    const float* deg = (const float*)d_in[1];
    const float* w1  = (const float*)d_in[2];
    const float* b1  = (const float*)d_in[3];
    const float* w2  = (const float*)d_in[4];
    const float* b2  = (const float*)d_in[5];
    const int* er    = (const int*)d_in[6];
    const int* ec    = (const int*)d_in[7];
    float* out = (float*)d_out;

    char* ws = (char*)d_ws;
    int*   cols_pad = (int*)(ws);                    // 12.8 MB  [NOWNED x CAP]
    int*   cnt      = (int*)(ws + 12800000);         // 200 KB
    float* agg1     = (float*)(ws + 13107200);       // 25.6 MB  [NOWNED x 128]
    float* z        = (float*)(ws + 38707200);       // 25.6 MB  [NOWNED x 128]
    float* h2       = (float*)(ws + 13107200);       // 12.8 MB (aliases dead agg1)

    // ---- padded-CSR build (no hist, no scan) ----
    hipMemsetAsync(cnt, 0, NOWNED * sizeof(int), stream);
    fill_k<<<(NEDGES + 255) / 256, 256, 0, stream>>>(er, ec, cnt, cols_pad);

    // ---- layer 1 ----
    gather1_k<<<(NOWNED * 64 + 255) / 256, 256, 0, stream>>>(x, deg, cnt, cols_pad, agg1);
    gemm1_k<<<(NOWNED + 63) / 64, 256, 0, stream>>>(agg1, w1, b1, deg, z);

    // ---- layer 2 ----  (agg1 dead; h2 aliases it)
    gemm2_k<<<(NOWNED + 127) / 128, 256, 0, stream>>>(z, w2, h2);
    gather2_k<<<(NOWNED * 64 + 255) / 256, 256, 0, stream>>>(h2, deg, b2, cnt, cols_pad, out);
}

// Round 4
// 277.201 us; speedup vs baseline: 3.2832x; 1.0564x over previous
//
#include <hip/hip_runtime.h>

#define NLOCAL 55000
#define NOWNED 50000
#define NEDGES 800000
#define INC 128
#define HIDC 128
#define OUTC 64
#define CAP 64           // padded-CSR bucket capacity (max degree; P(exceed) ~ 1e-15)

typedef unsigned short ushort_t;
typedef unsigned int uint_t;

static __device__ __forceinline__ ushort_t f2bf(float f) {   // RNE fp32->bf16
    uint_t u = __float_as_uint(f);
    return (ushort_t)((u + 0x7FFFu + ((u >> 16) & 1u)) >> 16);
}
static __device__ __forceinline__ float bf2f(ushort_t s) {
    return __uint_as_float(((uint_t)s) << 16);
}

// ================= prep: xd = bf16(deg[row] * x[row])  [NLOCAL x 128] =================
__global__ __launch_bounds__(256) void prep_k(const float* __restrict__ x,
                                              const float* __restrict__ deg,
                                              ushort_t* __restrict__ xd) {
    const int gid = blockIdx.x * 256 + threadIdx.x;   // one float4 -> 4 bf16 each
    if (gid >= NLOCAL * 32) return;
    const int row = gid >> 5;
    const int c0 = (gid & 31) << 2;
    const float d = deg[row];
    const float4 v = *(const float4*)(x + (size_t)row * INC + c0);
    uint_t lo = (uint_t)f2bf(v.x * d) | ((uint_t)f2bf(v.y * d) << 16);
    uint_t hi = (uint_t)f2bf(v.z * d) | ((uint_t)f2bf(v.w * d) << 16);
    *(uint2*)(xd + (size_t)row * INC + c0) = make_uint2(lo, hi);
}

// ================= padded-CSR build =================
__global__ __launch_bounds__(256) void fill_k(const int* __restrict__ er,
                                              const int* __restrict__ ec,
                                              int* __restrict__ cnt,
                                              int* __restrict__ cols_pad) {
    const int e = blockIdx.x * 256 + threadIdx.x;
    if (e >= NEDGES) return;
    const int row = er[e];
    if (row >= NOWNED) return;                  // only owned destination rows matter
    const int p = atomicAdd(&cnt[row], 1);
    if (p < CAP) cols_pad[row * CAP + p] = ec[e];
}

// ================= layer-1 gather: agg1[r] = sum_e xd[col]  (128 ch, bf16 in / fp32 out) ====
__global__ __launch_bounds__(256) void gather1_k(const ushort_t* __restrict__ xd,
                                                 const int* __restrict__ cnt,
                                                 const int* __restrict__ cols_pad,
                                                 float* __restrict__ agg1) {
    const int w = (blockIdx.x * 256 + threadIdx.x) >> 6;
    const int lane = threadIdx.x & 63;
    if (w >= NOWNED) return;
    int n = cnt[w];
    n = (n > CAP) ? CAP : n;
    const int mycol = (lane < n) ? cols_pad[w * CAP + lane] : 0;
    float ax = 0.f, ay = 0.f;
    for (int e = 0; e < n; ++e) {
        const int col = __shfl(mycol, e);
        const uint_t v = *(const uint_t*)(xd + (size_t)col * INC + lane * 2);
        ax += __uint_as_float(v << 16);          // bf16 ch0
        ay += __uint_as_float(v & 0xFFFF0000u);  // bf16 ch1
    }
    *(float2*)(agg1 + (size_t)w * INC + lane * 2) = make_float2(ax, ay);
}

// ================= gemm1: z = relu(d*(agg1@w1)+b1)*d  [NOWNED x 128, fp32] =================
__global__ __launch_bounds__(256) void gemm1_k(const float* __restrict__ agg1,
                                               const float* __restrict__ w1,
                                               const float* __restrict__ b1,
                                               const float* __restrict__ deg,
                                               float* __restrict__ z) {
    __shared__ float lds[64][132];
    const int t = threadIdx.x;
    const int r0 = blockIdx.x * 64;
    #pragma unroll
    for (int i = 0; i < 8; ++i) {
        const int idx = t + i * 256;
        const int r = idx >> 5;
        const int k0 = (idx & 31) << 2;
        const int gr = r0 + r;
        float4 v = make_float4(0.f, 0.f, 0.f, 0.f);
        if (gr < NOWNED) v = *(const float4*)(agg1 + (size_t)gr * INC + k0);
        *(float4*)(&lds[r][k0]) = v;
    }
    __syncthreads();
    const int cg = t & 15;
    const int rg = t >> 4;
    float acc[4][8];
    #pragma unroll
    for (int i = 0; i < 4; ++i)
        #pragma unroll
        for (int j = 0; j < 8; ++j) acc[i][j] = 0.f;

    #pragma unroll 8
    for (int k = 0; k < 128; ++k) {
        float av[4];
        #pragma unroll
        for (int i = 0; i < 4; ++i) av[i] = lds[rg * 4 + i][k];
        const float* wp = w1 + k * HIDC + cg * 8;
        const float4 w0 = *(const float4*)wp;
        const float4 w1v = *(const float4*)(wp + 4);
        const float wv[8] = {w0.x, w0.y, w0.z, w0.w, w1v.x, w1v.y, w1v.z, w1v.w};
        #pragma unroll
        for (int i = 0; i < 4; ++i)
            #pragma unroll
            for (int j = 0; j < 8; ++j)
                acc[i][j] = fmaf(av[i], wv[j], acc[i][j]);
    }
    #pragma unroll
    for (int i = 0; i < 4; ++i) {
        const int gr = r0 + rg * 4 + i;
        if (gr >= NOWNED) continue;
        const float di = deg[gr];
        float o[8];
        #pragma unroll
        for (int j = 0; j < 8; ++j) {
            const int gc = cg * 8 + j;
            float v = fmaf(di, acc[i][j], b1[gc]);
            o[j] = fmaxf(v, 0.f) * di;   // relu + fold layer-2's left d-scale
        }
        float4* zp = (float4*)(z + (size_t)gr * HIDC + cg * 8);
        zp[0] = make_float4(o[0], o[1], o[2], o[3]);
        zp[1] = make_float4(o[4], o[5], o[6], o[7]);
    }
}

// ================= gemm2: h2 = bf16(z @ w2)  [NOWNED x 64] =================
__global__ __launch_bounds__(256) void gemm2_k(const float* __restrict__ zz,
                                               const float* __restrict__ w2,
                                               ushort_t* __restrict__ h2) {
    __shared__ float lds[128][132];
    const int t = threadIdx.x;
    const int r0 = blockIdx.x * 128;
    #pragma unroll
    for (int i = 0; i < 16; ++i) {
        const int idx = t + i * 256;
        const int r = idx >> 5;
        const int k0 = (idx & 31) << 2;
        const int gr = r0 + r;
        float4 v = make_float4(0.f, 0.f, 0.f, 0.f);
        if (gr < NOWNED) v = *(const float4*)(zz + (size_t)gr * HIDC + k0);
        *(float4*)(&lds[r][k0]) = v;
    }
    __syncthreads();
    const int cg = t & 15;
    const int rg = t >> 4;
    float acc[8][4];
    #pragma unroll
    for (int i = 0; i < 8; ++i)
        #pragma unroll
        for (int j = 0; j < 4; ++j) acc[i][j] = 0.f;

    #pragma unroll 8
    for (int k = 0; k < 128; ++k) {
        float av[8];
        #pragma unroll
        for (int i = 0; i < 8; ++i) av[i] = lds[rg * 8 + i][k];
        const float4 wv = *(const float4*)(w2 + k * OUTC + cg * 4);
        const float wj[4] = {wv.x, wv.y, wv.z, wv.w};
        #pragma unroll
        for (int i = 0; i < 8; ++i)
            #pragma unroll
            for (int j = 0; j < 4; ++j)
                acc[i][j] = fmaf(av[i], wj[j], acc[i][j]);
    }
    #pragma unroll
    for (int i = 0; i < 8; ++i) {
        const int gr = r0 + rg * 8 + i;
        if (gr >= NOWNED) continue;
        uint_t lo = (uint_t)f2bf(acc[i][0]) | ((uint_t)f2bf(acc[i][1]) << 16);
        uint_t hi = (uint_t)f2bf(acc[i][2]) | ((uint_t)f2bf(acc[i][3]) << 16);
        *(uint2*)(h2 + (size_t)gr * OUTC + cg * 4) = make_uint2(lo, hi);
    }
}

// ================= layer-2 gather + epilogue: out[r] = deg[r]*sum(h2[col]) + b2 =================
__global__ __launch_bounds__(256) void gather2_k(const ushort_t* __restrict__ h2,
                                                 const float* __restrict__ deg,
                                                 const float* __restrict__ b2,
                                                 const int* __restrict__ cnt,
                                                 const int* __restrict__ cols_pad,
                                                 float* __restrict__ out) {
    const int w = (blockIdx.x * 256 + threadIdx.x) >> 6;
    const int lane = threadIdx.x & 63;
    if (w >= NOWNED) return;
    int n = cnt[w];
    n = (n > CAP) ? CAP : n;
    int c = (lane < n) ? cols_pad[w * CAP + lane] : 0;
    const float mywgt = (lane < n && c < NOWNED) ? 1.f : 0.f;  // x2 halo rows are zero
    if (c >= NOWNED) c = 0;                                    // clamp for safe load
    float acc = 0.f;
    int e = 0;
    for (; e + 1 < n; e += 2) {
        const int c0 = __shfl(c, e);
        const int c1 = __shfl(c, e + 1);
        const float w0 = __shfl(mywgt, e);
        const float w1 = __shfl(mywgt, e + 1);
        const float f0 = bf2f(h2[(size_t)c0 * OUTC + lane]);
        const float f1 = bf2f(h2[(size_t)c1 * OUTC + lane]);
        acc = fmaf(w0, f0, acc);
        acc = fmaf(w1, f1, acc);
    }
    if (e < n) {
        const int c0 = __shfl(c, e);
        const float w0 = __shfl(mywgt, e);
        acc = fmaf(w0, bf2f(h2[(size_t)c0 * OUTC + lane]), acc);
    }
    out[(size_t)w * OUTC + lane] = fmaf(deg[w], acc, b2[lane]);
}

extern "C" void kernel_launch(void* const* d_in, const int* in_sizes, int n_in,
                              void* d_out, int out_size, void* d_ws, size_t ws_size,
                              hipStream_t stream) {
    const float* x   = (const float*)d_in[0];
    const float* deg = (const float*)d_in[1];
    const float* w1  = (const float*)d_in[2];
    const float* b1  = (const float*)d_in[3];
    const float* w2  = (const float*)d_in[4];
    const float* b2  = (const float*)d_in[5];
    const int* er    = (const int*)d_in[6];
    const int* ec    = (const int*)d_in[7];
    float* out = (float*)d_out;

    char* ws = (char*)d_ws;
    // region A: xd (14.08 MB) lives here until gather1; z (25.6 MB) reuses it after
    ushort_t* xd    = (ushort_t*)(ws);                 // 14.08 MB [NLOCAL x 128] bf16
    float*    z     = (float*)(ws);                    // 25.6 MB  [NOWNED x 128] (aliases dead xd)
    int* cols_pad   = (int*)(ws + 25600000);           // 12.8 MB  [NOWNED x CAP]
    int* cnt        = (int*)(ws + 38400000);           // 200 KB
    float* agg1     = (float*)(ws + 38600192);         // 25.6 MB  [NOWNED x 128]
    ushort_t* h2    = (ushort_t*)(ws + 38600192);      // 6.4 MB   (aliases dead agg1)

    // ---- staging + padded-CSR build ----
    hipMemsetAsync(cnt, 0, NOWNED * sizeof(int), stream);
    prep_k<<<(NLOCAL * 32 + 255) / 256, 256, 0, stream>>>(x, deg, xd);
    fill_k<<<(NEDGES + 255) / 256, 256, 0, stream>>>(er, ec, cnt, cols_pad);

    // ---- layer 1 ----
    gather1_k<<<(NOWNED * 64 + 255) / 256, 256, 0, stream>>>(xd, cnt, cols_pad, agg1);
    gemm1_k<<<(NOWNED + 63) / 64, 256, 0, stream>>>(agg1, w1, b1, deg, z);   // z overwrites xd (dead)

    // ---- layer 2 ----  (agg1 dead; h2 aliases it)
    gemm2_k<<<(NOWNED + 127) / 128, 256, 0, stream>>>(z, w2, h2);
    gather2_k<<<(NOWNED * 64 + 255) / 256, 256, 0, stream>>>(h2, deg, b2, cnt, cols_pad, out);
}

// Round 5
// 242.798 us; speedup vs baseline: 3.7484x; 1.1417x over previous
//
#include <hip/hip_runtime.h>

#define NLOCAL 55000
#define NOWNED 50000
#define NEDGES 800000
#define INC 128
#define HIDC 128
#define OUTC 64
#define CAP 64           // padded-CSR bucket capacity (max degree; P(exceed) ~ 1e-15)
#define NSTRIPS (NOWNED / 16)   // 3125 exact

typedef unsigned short ushort_t;
typedef unsigned int uint_t;
typedef short short8_t __attribute__((ext_vector_type(8)));
typedef float float4_t __attribute__((ext_vector_type(4)));

static __device__ __forceinline__ ushort_t f2bf(float f) {   // RNE fp32->bf16
    uint_t u = __float_as_uint(f);
    return (ushort_t)((u + 0x7FFFu + ((u >> 16) & 1u)) >> 16);
}
static __device__ __forceinline__ float bflo(uint_t v) { return __uint_as_float(v << 16); }
static __device__ __forceinline__ float bfhi(uint_t v) { return __uint_as_float(v & 0xFFFF0000u); }

// ================= prep: xd = bf16(deg[row] * x[row])  [NLOCAL x 128] =================
__global__ __launch_bounds__(256) void prepx_k(const float* __restrict__ x,
                                               const float* __restrict__ deg,
                                               ushort_t* __restrict__ xd) {
    const int gid = blockIdx.x * 256 + threadIdx.x;   // one float4 -> 4 bf16 each
    if (gid >= NLOCAL * 32) return;
    const int row = gid >> 5;
    const int c0 = (gid & 31) << 2;
    const float d = deg[row];
    const float4 v = *(const float4*)(x + (size_t)row * INC + c0);
    uint_t lo = (uint_t)f2bf(v.x * d) | ((uint_t)f2bf(v.y * d) << 16);
    uint_t hi = (uint_t)f2bf(v.z * d) | ((uint_t)f2bf(v.w * d) << 16);
    *(uint2*)(xd + (size_t)row * INC + c0) = make_uint2(lo, hi);
}

// ============ prep: w1t[n][k] = bf16(w1[k][n]), w2t[n][k] = bf16(w2[k][n]) ============
__global__ __launch_bounds__(256) void prepw_k(const float* __restrict__ w1,
                                               const float* __restrict__ w2,
                                               ushort_t* __restrict__ w1t,
                                               ushort_t* __restrict__ w2t) {
    const int id = blockIdx.x * 256 + threadIdx.x;
    if (id < HIDC * INC) {                 // 16384: w1 [K=128][N=128]
        const int k = id >> 7, n = id & 127;
        w1t[n * 128 + k] = f2bf(w1[id]);
    } else if (id < HIDC * INC + HIDC * OUTC) {   // 8192: w2 [K=128][N=64]
        const int j = id - HIDC * INC;
        const int k = j >> 6, n = j & 63;
        w2t[n * 128 + k] = f2bf(w2[j]);
    }
}

// ================= padded-CSR build =================
__global__ __launch_bounds__(256) void fill_k(const int* __restrict__ er,
                                              const int* __restrict__ ec,
                                              int* __restrict__ cnt,
                                              int* __restrict__ cols_pad) {
    const int e = blockIdx.x * 256 + threadIdx.x;
    if (e >= NEDGES) return;
    const int row = er[e];
    if (row >= NOWNED) return;                  // only owned destination rows matter
    const int p = atomicAdd(&cnt[row], 1);
    if (p < CAP) cols_pad[row * CAP + p] = ec[e];
}

// ========== layer-1 gather: agg1b[r] = bf16(sum_e xd[col])  (128 ch) ==========
// one wave per row; scalar (s_load) col fetches; 2 edges/iter (lane halves);
// 4 channels/lane via uint2; fp32 accumulate, bf16 out
__global__ __launch_bounds__(256) void gather1_k(const ushort_t* __restrict__ xd,
                                                 const int* __restrict__ cnt,
                                                 const int* __restrict__ cols_pad,
                                                 ushort_t* __restrict__ agg1b) {
    const int w = __builtin_amdgcn_readfirstlane((blockIdx.x * 256 + threadIdx.x) >> 6);
    if (w >= NOWNED) return;
    const int lane = threadIdx.x & 63;
    int n = cnt[w];
    n = (n > CAP) ? CAP : n;
    const int* cp = cols_pad + w * CAP;         // wave-uniform base -> scalar loads
    const int half = lane >> 5;                 // 0: even edge, 1: odd edge
    const int ch = (lane & 31) << 2;            // 4 channels per lane
    float a0 = 0.f, a1 = 0.f, a2 = 0.f, a3 = 0.f;
    for (int e = 0; e < n; e += 2) {
        const int c0 = cp[e];
        const int c1 = (e + 1 < n) ? cp[e + 1] : -1;
        int myc = half ? c1 : c0;
        const float wgt = (myc >= 0) ? 1.f : 0.f;
        myc = (myc >= 0) ? myc : 0;
        const uint2 v = *(const uint2*)(xd + (size_t)myc * INC + ch);
        a0 = fmaf(wgt, bflo(v.x), a0);
        a1 = fmaf(wgt, bfhi(v.x), a1);
        a2 = fmaf(wgt, bflo(v.y), a2);
        a3 = fmaf(wgt, bfhi(v.y), a3);
    }
    // fold odd-edge half into even-edge half
    a0 += __shfl(a0, lane + 32);
    a1 += __shfl(a1, lane + 32);
    a2 += __shfl(a2, lane + 32);
    a3 += __shfl(a3, lane + 32);
    if (lane < 32) {
        uint_t lo = (uint_t)f2bf(a0) | ((uint_t)f2bf(a1) << 16);
        uint_t hi = (uint_t)f2bf(a2) | ((uint_t)f2bf(a3) << 16);
        *(uint2*)(agg1b + (size_t)w * INC + ch) = make_uint2(lo, hi);
    }
}

// ===== gemm1 (MFMA): zb = bf16( relu(d*(agg1b@w1)+b1) * d )  [NOWNED x 128] =====
// wave = one 16-row strip x 128 cols; 4 k-steps x 8 n-tiles of 16x16x32 bf16 MFMA
__global__ __launch_bounds__(256) void gemm1_k(const ushort_t* __restrict__ agg1b,
                                               const ushort_t* __restrict__ w1t,
                                               const float* __restrict__ b1,
                                               const float* __restrict__ deg,
                                               ushort_t* __restrict__ zb) {
    const int wave = threadIdx.x >> 6, lane = threadIdx.x & 63;
    const int strip = blockIdx.x * 4 + wave;
    if (strip >= NSTRIPS) return;
    const int row0 = strip * 16;
    const int m = lane & 15, q = lane >> 4;
    float4_t acc[8];
    #pragma unroll
    for (int nt = 0; nt < 8; ++nt) acc[nt] = (float4_t){0.f, 0.f, 0.f, 0.f};

    #pragma unroll
    for (int ks = 0; ks < 4; ++ks) {
        const int k0 = ks * 32;
        const short8_t a = *(const short8_t*)(agg1b + (size_t)(row0 + m) * HIDC + k0 + q * 8);
        #pragma unroll
        for (int nt = 0; nt < 8; ++nt) {
            const short8_t b = *(const short8_t*)(w1t + (size_t)(nt * 16 + m) * HIDC + k0 + q * 8);
            acc[nt] = __builtin_amdgcn_mfma_f32_16x16x32_bf16(a, b, acc[nt], 0, 0, 0);
        }
    }
    #pragma unroll
    for (int reg = 0; reg < 4; ++reg) {
        const int row = row0 + q * 4 + reg;
        const float d = deg[row];
        #pragma unroll
        for (int nt = 0; nt < 8; ++nt) {
            const int col = nt * 16 + m;
            float v = fmaf(d, acc[nt][reg], b1[col]);
            v = fmaxf(v, 0.f) * d;               // relu + fold layer-2's left d-scale
            zb[(size_t)row * HIDC + col] = f2bf(v);
        }
    }
}

// ===== gemm2 (MFMA): h2 = bf16(zb @ w2)  [NOWNED x 64] =====
__global__ __launch_bounds__(256) void gemm2_k(const ushort_t* __restrict__ zb,
                                               const ushort_t* __restrict__ w2t,
                                               ushort_t* __restrict__ h2) {
    const int wave = threadIdx.x >> 6, lane = threadIdx.x & 63;
    const int strip = blockIdx.x * 4 + wave;
    if (strip >= NSTRIPS) return;
    const int row0 = strip * 16;
    const int m = lane & 15, q = lane >> 4;
    float4_t acc[4];
    #pragma unroll
    for (int nt = 0; nt < 4; ++nt) acc[nt] = (float4_t){0.f, 0.f, 0.f, 0.f};

    #pragma unroll
    for (int ks = 0; ks < 4; ++ks) {
        const int k0 = ks * 32;
        const short8_t a = *(const short8_t*)(zb + (size_t)(row0 + m) * HIDC + k0 + q * 8);
        #pragma unroll
        for (int nt = 0; nt < 4; ++nt) {
            const short8_t b = *(const short8_t*)(w2t + (size_t)(nt * 16 + m) * HIDC + k0 + q * 8);
            acc[nt] = __builtin_amdgcn_mfma_f32_16x16x32_bf16(a, b, acc[nt], 0, 0, 0);
        }
    }
    #pragma unroll
    for (int reg = 0; reg < 4; ++reg) {
        const int row = row0 + q * 4 + reg;
        #pragma unroll
        for (int nt = 0; nt < 4; ++nt) {
            h2[(size_t)row * OUTC + nt * 16 + m] = f2bf(acc[nt][reg]);
        }
    }
}

// ===== layer-2 gather + epilogue: out[r] = deg[r]*sum(h2[col<NOWNED]) + b2 =====
// scalar col fetches; 2 edges/iter; 2 channels/lane
__global__ __launch_bounds__(256) void gather2_k(const ushort_t* __restrict__ h2,
                                                 const float* __restrict__ deg,
                                                 const float* __restrict__ b2,
                                                 const int* __restrict__ cnt,
                                                 const int* __restrict__ cols_pad,
                                                 float* __restrict__ out) {
    const int w = __builtin_amdgcn_readfirstlane((blockIdx.x * 256 + threadIdx.x) >> 6);
    if (w >= NOWNED) return;
    const int lane = threadIdx.x & 63;
    int n = cnt[w];
    n = (n > CAP) ? CAP : n;
    const int* cp = cols_pad + w * CAP;
    const int half = lane >> 5;
    const int ch = (lane & 31) << 1;            // 2 channels per lane
    float a0 = 0.f, a1 = 0.f;
    for (int e = 0; e < n; e += 2) {
        const int c0 = cp[e];
        const int c1 = (e + 1 < n) ? cp[e + 1] : NOWNED;   // NOWNED => zero row
        int myc = half ? c1 : c0;
        const float wgt = (myc < NOWNED) ? 1.f : 0.f;      // halo rows of x2 are zero
        myc = (myc < NOWNED) ? myc : 0;
        const uint_t v = *(const uint_t*)(h2 + (size_t)myc * OUTC + ch);
        a0 = fmaf(wgt, bflo(v), a0);
        a1 = fmaf(wgt, bfhi(v), a1);
    }
    a0 += __shfl(a0, lane + 32);
    a1 += __shfl(a1, lane + 32);
    if (lane < 32) {
        const float d = deg[w];
        const float2 o = make_float2(fmaf(d, a0, b2[ch]), fmaf(d, a1, b2[ch + 1]));
        *(float2*)(out + (size_t)w * OUTC + ch) = o;
    }
}

extern "C" void kernel_launch(void* const* d_in, const int* in_sizes, int n_in,
                              void* d_out, int out_size, void* d_ws, size_t ws_size,
                              hipStream_t stream) {
    const float* x   = (const float*)d_in[0];
    const float* deg = (const float*)d_in[1];
    const float* w1  = (const float*)d_in[2];
    const float* b1  = (const float*)d_in[3];
    const float* w2  = (const float*)d_in[4];
    const float* b2  = (const float*)d_in[5];
    const int* er    = (const int*)d_in[6];
    const int* ec    = (const int*)d_in[7];
    float* out = (float*)d_out;

    char* ws = (char*)d_ws;
    ushort_t* xd    = (ushort_t*)(ws);                 // 14.08 MB [NLOCAL x 128] bf16
    ushort_t* zb    = (ushort_t*)(ws);                 // 12.8 MB (aliases dead xd)
    int* cols_pad   = (int*)(ws + 14090240);           // 12.8 MB  [NOWNED x CAP]
    int* cnt        = (int*)(ws + 26890240);           // 200 KB
    ushort_t* agg1b = (ushort_t*)(ws + 27090944);      // 12.8 MB  [NOWNED x 128] bf16
    ushort_t* h2    = (ushort_t*)(ws + 27090944);      // 6.4 MB  (aliases dead agg1b)
    ushort_t* w1t   = (ushort_t*)(ws + 39890944);      // 32 KB   [128 x 128] bf16
    ushort_t* w2t   = (ushort_t*)(ws + 39923712);      // 16 KB   [64 x 128] bf16

    // ---- staging + padded-CSR build ----
    hipMemsetAsync(cnt, 0, NOWNED * sizeof(int), stream);
    prepx_k<<<(NLOCAL * 32 + 255) / 256, 256, 0, stream>>>(x, deg, xd);
    prepw_k<<<(HIDC * INC + HIDC * OUTC + 255) / 256, 256, 0, stream>>>(w1, w2, w1t, w2t);
    fill_k<<<(NEDGES + 255) / 256, 256, 0, stream>>>(er, ec, cnt, cols_pad);

    // ---- layer 1 ----
    gather1_k<<<(NOWNED * 64 + 255) / 256, 256, 0, stream>>>(xd, cnt, cols_pad, agg1b);
    gemm1_k<<<(NSTRIPS + 3) / 4, 256, 0, stream>>>(agg1b, w1t, b1, deg, zb);  // zb overwrites dead xd

    // ---- layer 2 ---- (agg1b dead; h2 aliases it)
    gemm2_k<<<(NSTRIPS + 3) / 4, 256, 0, stream>>>(zb, w2t, h2);
    gather2_k<<<(NOWNED * 64 + 255) / 256, 256, 0, stream>>>(h2, deg, b2, cnt, cols_pad, out);
}

// Round 6
// 212.757 us; speedup vs baseline: 4.2777x; 1.1412x over previous
//
#include <hip/hip_runtime.h>

#define NLOCAL 55000
#define NOWNED 50000
#define NEDGES 800000
#define INC 128
#define HIDC 128
#define OUTC 64
#define CAP 64            // padded-CSR bucket capacity (max degree; P(exceed) ~ 1e-15)
#define NSTRIPS (NOWNED / 16)   // 3125 exact
#define ZLD 136           // zt LDS row stride in shorts (+8 pad: phase-B ds_read 2-way/free)

typedef unsigned short ushort_t;
typedef unsigned int uint_t;
typedef short short8_t __attribute__((ext_vector_type(8)));
typedef float float4_t __attribute__((ext_vector_type(4)));

static __device__ __forceinline__ ushort_t f2bf(float f) {   // RNE fp32->bf16
    uint_t u = __float_as_uint(f);
    return (ushort_t)((u + 0x7FFFu + ((u >> 16) & 1u)) >> 16);
}
static __device__ __forceinline__ float bflo(uint_t v) { return __uint_as_float(v << 16); }
static __device__ __forceinline__ float bfhi(uint_t v) { return __uint_as_float(v & 0xFFFF0000u); }

// ======= prep (fused): xd = bf16(deg*x); zero cnt; transpose w1,w2 to bf16 [n][k] =======
__global__ __launch_bounds__(256) void prep_k(const float* __restrict__ x,
                                              const float* __restrict__ deg,
                                              const float* __restrict__ w1,
                                              const float* __restrict__ w2,
                                              ushort_t* __restrict__ xd,
                                              ushort_t* __restrict__ w1t,
                                              ushort_t* __restrict__ w2t,
                                              int* __restrict__ cnt) {
    const int gid = blockIdx.x * 256 + threadIdx.x;
    if (gid < NLOCAL * 32) {                 // one float4 -> 4 bf16
        const int row = gid >> 5;
        const int c0 = (gid & 31) << 2;
        const float d = deg[row];
        const float4 v = *(const float4*)(x + (size_t)row * INC + c0);
        uint_t lo = (uint_t)f2bf(v.x * d) | ((uint_t)f2bf(v.y * d) << 16);
        uint_t hi = (uint_t)f2bf(v.z * d) | ((uint_t)f2bf(v.w * d) << 16);
        *(uint2*)(xd + (size_t)row * INC + c0) = make_uint2(lo, hi);
    }
    if (gid < NOWNED) cnt[gid] = 0;
    if (gid < HIDC * INC) {                  // w1 [K=128][N=128] -> w1t [N][K]
        const int k = gid >> 7, n = gid & 127;
        w1t[n * 128 + k] = f2bf(w1[gid]);
    } else if (gid < HIDC * INC + HIDC * OUTC) {   // w2 [K=128][N=64] -> w2t [N][K]
        const int j = gid - HIDC * INC;
        const int k = j >> 6, n = j & 63;
        w2t[n * 128 + k] = f2bf(w2[j]);
    }
}

// ================= padded-CSR build =================
__global__ __launch_bounds__(256) void fill_k(const int* __restrict__ er,
                                              const int* __restrict__ ec,
                                              int* __restrict__ cnt,
                                              int* __restrict__ cols_pad) {
    const int e = blockIdx.x * 256 + threadIdx.x;
    if (e >= NEDGES) return;
    const int row = er[e];
    if (row >= NOWNED) return;                  // only owned destination rows matter
    const int p = atomicAdd(&cnt[row], 1);
    if (p < CAP) cols_pad[row * CAP + p] = ec[e];
}

// ========== layer-1 gather: agg1b[r] = bf16(sum_e xd[col])  (128 ch) ==========
// one wave per row; 4 edges/iter (16-lane quarters), uint4 = 8 ch/lane;
// wave-uniform scalar col loads, prefetched one int4 ahead; fp32 acc, bf16 out
__global__ __launch_bounds__(256) void gather1_k(const ushort_t* __restrict__ xd,
                                                 const int* __restrict__ cnt,
                                                 const int* __restrict__ cols_pad,
                                                 ushort_t* __restrict__ agg1b) {
    const int w = __builtin_amdgcn_readfirstlane((blockIdx.x * 256 + threadIdx.x) >> 6);
    if (w >= NOWNED) return;
    const int lane = threadIdx.x & 63;
    const int q4 = lane >> 4;                   // quarter: edge e+q4
    const int ch = (lane & 15) << 3;            // 8 channels per lane (16 B)
    int n = cnt[w];
    n = (n > CAP) ? CAP : n;
    const int4* cp4 = (const int4*)(cols_pad + w * CAP);   // wave-uniform -> s_load
    const int nIter = (n + 3) >> 2;
    float a0 = 0.f, a1 = 0.f, a2 = 0.f, a3 = 0.f, a4 = 0.f, a5 = 0.f, a6 = 0.f, a7 = 0.f;
    int4 cc = (nIter > 0) ? cp4[0] : make_int4(0, 0, 0, 0);
    for (int j = 0; j < nIter; ++j) {
        const int4 cn = cp4[(j + 1 < 16) ? j + 1 : 15];    // prefetch next (clamped)
        const int e = j * 4 + q4;
        int myc = (q4 == 0) ? cc.x : (q4 == 1) ? cc.y : (q4 == 2) ? cc.z : cc.w;
        const float wgt = (e < n) ? 1.f : 0.f;
        myc = (e < n) ? myc : 0;
        const uint4 v = *(const uint4*)(xd + (size_t)myc * INC + ch);
        a0 = fmaf(wgt, bflo(v.x), a0);  a1 = fmaf(wgt, bfhi(v.x), a1);
        a2 = fmaf(wgt, bflo(v.y), a2);  a3 = fmaf(wgt, bfhi(v.y), a3);
        a4 = fmaf(wgt, bflo(v.z), a4);  a5 = fmaf(wgt, bfhi(v.z), a5);
        a6 = fmaf(wgt, bflo(v.w), a6);  a7 = fmaf(wgt, bfhi(v.w), a7);
        cc = cn;
    }
    // fold the 4 quarters together
    a0 += __shfl_xor(a0, 16); a1 += __shfl_xor(a1, 16); a2 += __shfl_xor(a2, 16); a3 += __shfl_xor(a3, 16);
    a4 += __shfl_xor(a4, 16); a5 += __shfl_xor(a5, 16); a6 += __shfl_xor(a6, 16); a7 += __shfl_xor(a7, 16);
    a0 += __shfl_xor(a0, 32); a1 += __shfl_xor(a1, 32); a2 += __shfl_xor(a2, 32); a3 += __shfl_xor(a3, 32);
    a4 += __shfl_xor(a4, 32); a5 += __shfl_xor(a5, 32); a6 += __shfl_xor(a6, 32); a7 += __shfl_xor(a7, 32);
    if (lane < 16) {
        uint4 o;
        o.x = (uint_t)f2bf(a0) | ((uint_t)f2bf(a1) << 16);
        o.y = (uint_t)f2bf(a2) | ((uint_t)f2bf(a3) << 16);
        o.z = (uint_t)f2bf(a4) | ((uint_t)f2bf(a5) << 16);
        o.w = (uint_t)f2bf(a6) | ((uint_t)f2bf(a7) << 16);
        *(uint4*)(agg1b + (size_t)w * INC + ch) = o;
    }
}

// ===== fused gemm1+gemm2 (MFMA): h2 = bf16( relu(d*(agg1b@w1)+b1)*d @ w2 )  per 16-row strip =====
// block = 4 waves = one strip; gemm1 C-tile round-trips LDS (C-layout -> A-layout), feeds gemm2
__global__ __launch_bounds__(256) void gemm12_k(const ushort_t* __restrict__ agg1b,
                                                const ushort_t* __restrict__ w1t,
                                                const ushort_t* __restrict__ w2t,
                                                const float* __restrict__ b1,
                                                const float* __restrict__ deg,
                                                ushort_t* __restrict__ h2) {
    __shared__ ushort_t zt[16 * ZLD];           // 16 rows x 128 ch (+8 pad), 4.25 KB
    const int wv = threadIdx.x >> 6, lane = threadIdx.x & 63;
    const int strip = blockIdx.x;
    const int row0 = strip * 16;
    const int m = lane & 15, q = lane >> 4;

    // ---- phase A: z-tile = relu(d*(agg1b@w1)+b1)*d ; each wave does 2 of 8 n-tiles ----
    float4_t acc[2];
    acc[0] = (float4_t){0.f, 0.f, 0.f, 0.f};
    acc[1] = (float4_t){0.f, 0.f, 0.f, 0.f};
    #pragma unroll
    for (int ks = 0; ks < 4; ++ks) {
        const int k0 = ks * 32 + q * 8;
        const short8_t a = *(const short8_t*)(agg1b + (size_t)(row0 + m) * HIDC + k0);
        #pragma unroll
        for (int t = 0; t < 2; ++t) {
            const int nt = wv * 2 + t;
            const short8_t b = *(const short8_t*)(w1t + (size_t)(nt * 16 + m) * HIDC + k0);
            acc[t] = __builtin_amdgcn_mfma_f32_16x16x32_bf16(a, b, acc[t], 0, 0, 0);
        }
    }
    #pragma unroll
    for (int reg = 0; reg < 4; ++reg) {
        const int r = q * 4 + reg;              // row within strip
        const float d = deg[row0 + r];
        #pragma unroll
        for (int t = 0; t < 2; ++t) {
            const int col = (wv * 2 + t) * 16 + m;
            float v = fmaf(d, acc[t][reg], b1[col]);
            zt[r * ZLD + col] = f2bf(fmaxf(v, 0.f) * d);   // relu + fold layer-2 left d-scale
        }
    }
    __syncthreads();

    // ---- phase B: h2-tile = z @ w2 ; each wave does 1 of 4 n-tiles ----
    float4_t acc2 = (float4_t){0.f, 0.f, 0.f, 0.f};
    #pragma unroll
    for (int ks = 0; ks < 4; ++ks) {
        const int k0 = ks * 32 + q * 8;
        const short8_t a = *(const short8_t*)(&zt[m * ZLD + k0]);
        const short8_t b = *(const short8_t*)(w2t + (size_t)(wv * 16 + m) * HIDC + k0);
        acc2 = __builtin_amdgcn_mfma_f32_16x16x32_bf16(a, b, acc2, 0, 0, 0);
    }
    #pragma unroll
    for (int reg = 0; reg < 4; ++reg) {
        const int row = row0 + q * 4 + reg;
        h2[(size_t)row * OUTC + wv * 16 + m] = f2bf(acc2[reg]);
    }
}

// ===== layer-2 gather + epilogue: out[r] = deg[r]*sum(h2[col<NOWNED]) + b2 =====
// 4 edges/iter (quarters), uint2 = 4 ch/lane; scalar col loads w/ prefetch
__global__ __launch_bounds__(256) void gather2_k(const ushort_t* __restrict__ h2,
                                                 const float* __restrict__ deg,
                                                 const float* __restrict__ b2,
                                                 const int* __restrict__ cnt,
                                                 const int* __restrict__ cols_pad,
                                                 float* __restrict__ out) {
    const int w = __builtin_amdgcn_readfirstlane((blockIdx.x * 256 + threadIdx.x) >> 6);
    if (w >= NOWNED) return;
    const int lane = threadIdx.x & 63;
    const int q4 = lane >> 4;
    const int ch = (lane & 15) << 2;            // 4 channels per lane (8 B)
    int n = cnt[w];
    n = (n > CAP) ? CAP : n;
    const int4* cp4 = (const int4*)(cols_pad + w * CAP);
    const int nIter = (n + 3) >> 2;
    float a0 = 0.f, a1 = 0.f, a2 = 0.f, a3 = 0.f;
    int4 cc = (nIter > 0) ? cp4[0] : make_int4(0, 0, 0, 0);
    for (int j = 0; j < nIter; ++j) {
        const int4 cn = cp4[(j + 1 < 16) ? j + 1 : 15];
        const int e = j * 4 + q4;
        int myc = (q4 == 0) ? cc.x : (q4 == 1) ? cc.y : (q4 == 2) ? cc.z : cc.w;
        const float wgt = (e < n && myc < NOWNED) ? 1.f : 0.f;  // halo rows of x2 are zero
        myc = (e < n && myc < NOWNED) ? myc : 0;
        const uint2 v = *(const uint2*)(h2 + (size_t)myc * OUTC + ch);
        a0 = fmaf(wgt, bflo(v.x), a0);  a1 = fmaf(wgt, bfhi(v.x), a1);
        a2 = fmaf(wgt, bflo(v.y), a2);  a3 = fmaf(wgt, bfhi(v.y), a3);
        cc = cn;
    }
    a0 += __shfl_xor(a0, 16); a1 += __shfl_xor(a1, 16); a2 += __shfl_xor(a2, 16); a3 += __shfl_xor(a3, 16);
    a0 += __shfl_xor(a0, 32); a1 += __shfl_xor(a1, 32); a2 += __shfl_xor(a2, 32); a3 += __shfl_xor(a3, 32);
    if (lane < 16) {
        const float d = deg[w];
        const float4 o = make_float4(fmaf(d, a0, b2[ch]),     fmaf(d, a1, b2[ch + 1]),
                                     fmaf(d, a2, b2[ch + 2]), fmaf(d, a3, b2[ch + 3]));
        *(float4*)(out + (size_t)w * OUTC + ch) = o;
    }
}

extern "C" void kernel_launch(void* const* d_in, const int* in_sizes, int n_in,
                              void* d_out, int out_size, void* d_ws, size_t ws_size,
                              hipStream_t stream) {
    const float* x   = (const float*)d_in[0];
    const float* deg = (const float*)d_in[1];
    const float* w1  = (const float*)d_in[2];
    const float* b1  = (const float*)d_in[3];
    const float* w2  = (const float*)d_in[4];
    const float* b2  = (const float*)d_in[5];
    const int* er    = (const int*)d_in[6];
    const int* ec    = (const int*)d_in[7];
    float* out = (float*)d_out;

    char* ws = (char*)d_ws;
    ushort_t* xd    = (ushort_t*)(ws);                 // 14.08 MB [NLOCAL x 128] bf16
    int* cols_pad   = (int*)(ws + 14090240);           // 12.8 MB  [NOWNED x CAP]
    int* cnt        = (int*)(ws + 26890240);           // 200 KB
    ushort_t* agg1b = (ushort_t*)(ws + 27090944);      // 12.8 MB  [NOWNED x 128] bf16
    ushort_t* h2    = (ushort_t*)(ws + 39891200);      // 6.4 MB   [NOWNED x 64] bf16
    ushort_t* w1t   = (ushort_t*)(ws + 46291456);      // 32 KB    [128 x 128] bf16
    ushort_t* w2t   = (ushort_t*)(ws + 46324224);      // 16 KB    [64 x 128] bf16

    // prep (xd, w1t, w2t, cnt=0) -> CSR fill -> gather1 -> fused gemms -> gather2
    prep_k<<<(NLOCAL * 32 + 255) / 256, 256, 0, stream>>>(x, deg, w1, w2, xd, w1t, w2t, cnt);
    fill_k<<<(NEDGES + 255) / 256, 256, 0, stream>>>(er, ec, cnt, cols_pad);
    gather1_k<<<(NOWNED * 64 + 255) / 256, 256, 0, stream>>>(xd, cnt, cols_pad, agg1b);
    gemm12_k<<<NSTRIPS, 256, 0, stream>>>(agg1b, w1t, w2t, b1, deg, h2);
    gather2_k<<<(NOWNED * 64 + 255) / 256, 256, 0, stream>>>(h2, deg, b2, cnt, cols_pad, out);
}